// Round 8
// baseline (57.029 us; speedup 1.0000x reference)
//
#include <hip/hip_runtime.h>

#define LN_EPS 1e-5f

// ---------------------------------------------------------------------------
// Index algebra (verified passing rounds 2-7):
//   F[which][b][g][cc][cs*64+d] = P_{which}[b, s_i, h_i*64+d] + bias
//     s_i = (cc<2 ? 240+8*cc : 8*(cc-2)) + cs,  h_i = g*2 + (cc>>1)
//   Dt[b][gq][gk][cc][cs] = dot64(Fq, Fk) / 8
//   SFK[b][c][d] = 32 * sum_gv FK[b][gv][c>>3][(c&7)*64+d]   (pre-scaled)
//   attn: per (q,k) softmax over 32 c of (vq&vk ? Dt : 0); masked -> 1/32.
//   A[c] = sum_k attn;  ctx[b,q,h*64+d] = sum_c A[c]*SFK[b][c][d].
//   attn_out == 1.0 everywhere.
// Perf law (r2/r5/r7 post-mortem): the 39us kernels were LATENCY-STARVED —
// few waves (<=2/SIMD) each streaming a DISTINCT multi-100KB slice (zero L1
// reuse, ~1 load-group in flight => ~150 GB/s). Fast kernels either share
// the same weight slice across all waves of a block (L1 x8 reuse, kP) or
// run >=8 waves/CU. Rule: per-wave streams must be L1/L2-hot AND >=4
// waves/SIMD resident.
// ---------------------------------------------------------------------------

__device__ __forceinline__ bool sniff_mask_bytes(const unsigned int* m) {
    unsigned int acc = 0;
#pragma unroll
    for (int i = 0; i < 16; ++i) acc |= m[i];
    return acc > 1u;
}

// kP: projections -> F.  64 blocks x 512 thr.  All 8 waves of a block share
// one 128KB W column-slice (L1-resident after first wave) => fast (<=4us).
__global__ __launch_bounds__(512) void kP_proj(
    const float* __restrict__ Qin, const float* __restrict__ Kin,
    const float* __restrict__ WQ, const float* __restrict__ bQ,
    const float* __restrict__ WK, const float* __restrict__ bK,
    float* __restrict__ F)
{
    int bx = blockIdx.x;
    int h_i = bx & 7, b = (bx >> 3) & 1, which = bx >> 4;
    int g = h_i >> 1, cc2 = (h_i & 1) * 2;
    int t = threadIdx.x;

    const float* In   = which ? Kin : Qin;
    const float* W    = which ? WK  : WQ;
    const float* bias = which ? bK  : bQ;

    __shared__ float Xl[16][512];
    int sb0 = (h_i & 1) ? 0 : 240;
#pragma unroll
    for (int i = 0; i < 4; ++i) {
        int idx = (i * 512 + t);
        int rl = idx >> 7, m4 = idx & 127;
        int srow = sb0 + (rl >> 3) * 8 + (rl & 7);
        ((float4*)&Xl[rl][0])[m4] =
            ((const float4*)&In[(b * 256 + srow) * 512])[m4];
    }
    __syncthreads();

    int d = t & 63, rr = t >> 6;
    int n = h_i * 64 + d;
    float acc0 = 0.f, acc1 = 0.f;
    const float* wp = W + n;
#pragma unroll 8
    for (int m = 0; m < 512; ++m) {
        float w = wp[m * 512];
        acc0 += Xl[rr][m] * w;
        acc1 += Xl[rr + 8][m] * w;
    }
    float bb = bias[n];
    int base = ((which * 2 + b) * 4 + g) * 4;
    F[(base + cc2)     * 512 + rr * 64 + d] = acc0 + bb;
    F[(base + cc2 + 1) * 512 + rr * 64 + d] = acc1 + bb;
}

// kC: Dt (8-lane dots + shfl) and SFK (pre-scaled x32).  48 blocks x 256 thr.
__global__ void kC_dtab_sfk(const float* __restrict__ F, float* __restrict__ Dt,
                            float* __restrict__ SFK) {
    int slot = blockIdx.x * 256 + threadIdx.x;
    if (slot < 8192) {
        int part = slot & 7, e = slot >> 3;
        int cs = e & 7, cc = (e >> 3) & 3, gk = (e >> 5) & 3,
            gq = (e >> 7) & 3, b = (e >> 9) & 1;
        const float* fq = F + ((b * 4 + gq) * 4 + cc) * 512 + cs * 64 + part * 8;
        const float* fk = F + (((2 + b) * 4 + gk) * 4 + cc) * 512 + cs * 64 + part * 8;
        float a = 0.f;
#pragma unroll
        for (int u = 0; u < 8; ++u) a += fq[u] * fk[u];
        a += __shfl_xor(a, 1);
        a += __shfl_xor(a, 2);
        a += __shfl_xor(a, 4);
        if (part == 0) Dt[e] = a * 0.125f;
    } else {
        int e = slot - 8192;
        int d = e & 63, c = (e >> 6) & 31, b = e >> 11;
        float a = 0.f;
#pragma unroll
        for (int gv = 0; gv < 4; ++gv)
            a += F[(((2 + b) * 4 + gv) * 4 + (c >> 3)) * 512 + (c & 7) * 64 + d];
        SFK[e] = 32.f * a;
    }
}

// kAttn: 1024 blocks x 256 thr.  Wave per (h,q); 2 lanes per k, 16 c each.
// Writes ctx directly.  Optionally fills attnp with 1.0.
__global__ void kAttn(const float* __restrict__ Dt, const void* __restrict__ maskp,
                      const float* __restrict__ SFK, float* __restrict__ ctx,
                      float* __restrict__ attnp, int fill) {
    __shared__ float aws[4][32];
    int vb = blockIdx.x, t = threadIdx.x;
    if (fill) ((float4*)attnp)[vb * 256 + t] = make_float4(1.f, 1.f, 1.f, 1.f);
    int qb = vb & 63, h = (vb >> 6) & 7, b = vb >> 9;
    int wave = t >> 6, l = t & 63;
    int q = qb * 4 + wave;
    int half = l & 1, klo = l >> 1;
    int g_q = q & 3;
    int i_q = h * 32 + (q >> 3);
    bool up_q = (q & 4) == 0;
    int ak = klo & 3;
    bool up_k = (klo & 4) == 0;

    bool mbytes = sniff_mask_bytes((const unsigned int*)maskp);

    float sq[16];
    const float* Db = Dt + ((b * 4 + g_q) * 4 + ak) * 32 + half * 16;
#pragma unroll
    for (int j = 0; j < 16; ++j) {
        int cc = half * 2 + (j >> 3);
        int row = g_q * 64 + 30 + cc;
        bool vq = up_q ? (i_q >= 256 - row) : (i_q <= 255 - row);
        sq[j] = vq ? Db[j] : 0.f;
    }

    float A[16];
#pragma unroll
    for (int j = 0; j < 16; ++j) A[j] = 0.f;

    int qrow = (b * 256 + q) * 256;
    for (int r = 0; r < 8; ++r) {
        int k = r * 32 + klo;
        bool masked = mbytes ? (((const unsigned char*)maskp)[qrow + k] != 0)
                             : (((const int*)maskp)[qrow + k] != 0);
        if (masked) {
#pragma unroll
            for (int j = 0; j < 16; ++j) A[j] += 0.03125f;
            continue;
        }
        int i_k = h * 32 + (k >> 3);
        float s[16];
        float mx = -1e30f;
#pragma unroll
        for (int j = 0; j < 16; ++j) {
            int cc = half * 2 + (j >> 3);
            int row = ak * 64 + 30 + cc;
            bool vk = up_k ? (i_k >= 256 - row) : (i_k <= 255 - row);
            s[j] = vk ? sq[j] : 0.f;
            mx = fmaxf(mx, s[j]);
        }
        mx = fmaxf(mx, __shfl_xor(mx, 1));
        float den = 0.f;
#pragma unroll
        for (int j = 0; j < 16; ++j) { s[j] = __expf(s[j] - mx); den += s[j]; }
        den += __shfl_xor(den, 1);
        float inv = 1.f / den;
#pragma unroll
        for (int j = 0; j < 16; ++j) A[j] += s[j] * inv;
    }

#pragma unroll
    for (int off = 2; off < 64; off <<= 1) {
#pragma unroll
        for (int j = 0; j < 16; ++j) A[j] += __shfl_xor(A[j], off);
    }

    float* aw = aws[wave];
    if (l < 2) {
#pragma unroll
        for (int j = 0; j < 16; ++j) aw[l * 16 + j] = A[j];
    }
    float acc = 0.f;
    const float* S = SFK + b * 2048;
#pragma unroll
    for (int c = 0; c < 32; ++c) acc += aw[c] * S[c * 64 + l];
    ctx[(b * 256 + q) * 512 + h * 64 + l] = acc;
}

// kG3: y = ctx @ Wo + bo.  1024 blocks (128 rowquads x 8 colchunks) x 256 thr.
// 4096 waves = 16/CU; the 4 waves of a block read the SAME 64-col Wo slice
// (L1 reuse x4); ctx rows in LDS (broadcast); dual accs break the FMA chain.
__global__ __launch_bounds__(256) void kG3_wo(
    const float* __restrict__ ctx, const float* __restrict__ Wo,
    const float* __restrict__ bo, float* __restrict__ y)
{
    __shared__ float Cl[4][512];                 // 8 KB
    int bx = blockIdx.x;
    int cq = bx & 7, rq = bx >> 3;               // 8 colchunks x 128 rowquads
    int r0 = rq * 4, c0 = cq * 64;
    int t = threadIdx.x;

#pragma unroll
    for (int i = 0; i < 2; ++i) {
        int idx = i * 256 + t;                   // 512 float4 slots
        int r = idx >> 7, m4 = idx & 127;
        ((float4*)&Cl[r][0])[m4] = ((const float4*)&ctx[(r0 + r) * 512])[m4];
    }
    __syncthreads();

    int w = t >> 6, l = t & 63;
    int row = r0 + w, col = c0 + l;
    float acc0 = 0.f, acc1 = 0.f;
    const float* wp = Wo + col;
    const float* cl = Cl[w];
#pragma unroll 4
    for (int m = 0; m < 512; m += 2) {
        acc0 += cl[m]     * wp[m * 512];
        acc1 += cl[m + 1] * wp[(m + 1) * 512];
    }
    y[row * 512 + col] = acc0 + acc1 + bo[col];
}

// kLN3: y + Qin residual, LayerNorm -> out.  512 blocks x 256 thr.
__global__ void kLN3(const float* __restrict__ y, const float* __restrict__ Qin,
                     const float* __restrict__ gamma, const float* __restrict__ beta,
                     float* __restrict__ out) {
    __shared__ float red[8];
    int row = blockIdx.x, t = threadIdx.x;
    float y0 = y[row * 512 + t]       + Qin[row * 512 + t];
    float y1 = y[row * 512 + 256 + t] + Qin[row * 512 + 256 + t];
    float s1 = y0 + y1, s2 = y0 * y0 + y1 * y1;
#pragma unroll
    for (int off = 1; off < 64; off <<= 1) {
        s1 += __shfl_xor(s1, off);
        s2 += __shfl_xor(s2, off);
    }
    if ((t & 63) == 0) { red[(t >> 6) * 2] = s1; red[(t >> 6) * 2 + 1] = s2; }
    __syncthreads();
    float tot1 = red[0] + red[2] + red[4] + red[6];
    float tot2 = red[1] + red[3] + red[5] + red[7];
    float mu = tot1 * (1.f / 512.f);
    float var = tot2 * (1.f / 512.f) - mu * mu;
    float rs = rsqrtf(var + LN_EPS);
    out[row * 512 + t]       = (y0 - mu) * rs * gamma[t]       + beta[t];
    out[row * 512 + 256 + t] = (y1 - mu) * rs * gamma[t + 256] + beta[t + 256];
}

// plan-B only: restore attn_out region (which hosted scratch) to 1.0
__global__ void k5_fill(float* __restrict__ p, int n) {
    int i = (blockIdx.x * 256 + threadIdx.x) * 4;
    float4 one = make_float4(1.f, 1.f, 1.f, 1.f);
    for (; i < n; i += gridDim.x * 256 * 4) *(float4*)(p + i) = one;
}

extern "C" void kernel_launch(void* const* d_in, const int* in_sizes, int n_in,
                              void* d_out, int out_size, void* d_ws, size_t ws_size,
                              hipStream_t stream) {
    (void)in_sizes; (void)n_in; (void)out_size;
    const float* Qin  = (const float*)d_in[0];
    const float* Kin  = (const float*)d_in[1];
    const void*  mask = d_in[3];
    const float* WQ   = (const float*)d_in[4];
    const float* bQ   = (const float*)d_in[5];
    const float* WK   = (const float*)d_in[6];
    const float* bK   = (const float*)d_in[7];
    const float* Wo   = (const float*)d_in[10];
    const float* bo   = (const float*)d_in[11];
    const float* gamma= (const float*)d_in[12];
    const float* beta = (const float*)d_in[13];

    float* out   = (float*)d_out;
    float* attnp = out + 262144;                  // 1,048,576 floats (output 1)

    const size_t NEED = 562176ull * sizeof(float);
    int fill;
    float* scr;
    if (ws_size >= NEED) { scr = (float*)d_ws; fill = 1; }   // plan A
    else                 { scr = attnp;        fill = 0; }   // plan B

    float* F   = scr;                             // 32768
    float* Dt  = scr + 32768;                     // 1024
    float* SFK = scr + 33792;                     // 4096 (pre-scaled x32)
    float* ctx = scr + 37888;                     // 262144
    float* y   = scr + 300032;                    // 262144

    kP_proj    <<<dim3(64),   dim3(512), 0, stream>>>(Qin, Kin, WQ, bQ, WK, bK, F);
    kC_dtab_sfk<<<dim3(48),   dim3(256), 0, stream>>>(F, Dt, SFK);
    kAttn      <<<dim3(1024), dim3(256), 0, stream>>>(Dt, mask, SFK, ctx, attnp, fill);
    kG3_wo     <<<dim3(1024), dim3(256), 0, stream>>>(ctx, Wo, bo, y);
    kLN3       <<<dim3(512),  dim3(256), 0, stream>>>(y, Qin, gamma, beta, out);
    if (!fill) k5_fill<<<dim3(256), dim3(256), 0, stream>>>(attnp, 1048576);
}

// Round 9
// 45.106 us; speedup vs baseline: 1.2643x; 1.2643x over previous
//
#include <hip/hip_runtime.h>

#define LN_EPS 1e-5f

// ---------------------------------------------------------------------------
// Index algebra (verified passing rounds 2-8):
//   F[which][b][g][cc][cs*64+d] = P_{which}[b, s_i, h_i*64+d] + bias
//     s_i = (cc<2 ? 240+8*cc : 8*(cc-2)) + cs,  h_i = g*2 + (cc>>1)
//   Dt[b][gq][gk][cc][cs] = dot64(Fq, Fk) / 8
//   SFK[b][c][d] = 32 * sum_gv FK[b][gv][c>>3][(c&7)*64+d]   (pre-scaled)
//   attn: per (q,k) softmax over 32 c of (vq&vk ? Dt : 0); masked -> 1/32.
//   A[c] = sum_k attn;  ctx[b,q,h*64+d] = sum_c A[c]*SFK[b][c][d].
//   attn_out == 1.0 everywhere.
// PERF LAW (r2/r5/r7/r8): a per-thread loop of D column-strided (2KB-step)
// loads costs ~D x 180cy (~38us at D=512) — zero MLP, regardless of
// occupancy, L1 sharing, ILP or split-K width. Column walks are poison.
// Row-major float4 streaming (outer-product form) is the fix.
// Scratch: F 32768 | Dt 1024 | SFK 4096 | ctx 262144 = 300,032 floats.
// ---------------------------------------------------------------------------

#define FMA4(a, s, v) { (a).x += (s)*(v).x; (a).y += (s)*(v).y; \
                        (a).z += (s)*(v).z; (a).w += (s)*(v).w; }

__device__ __forceinline__ bool sniff_mask_bytes(const unsigned int* m) {
    unsigned int acc = 0;
#pragma unroll
    for (int i = 0; i < 16; ++i) acc |= m[i];
    return acc > 1u;
}

// kP: projections -> F.  64 blocks x 512 thr (8 waves share one W slice).
__global__ __launch_bounds__(512) void kP_proj(
    const float* __restrict__ Qin, const float* __restrict__ Kin,
    const float* __restrict__ WQ, const float* __restrict__ bQ,
    const float* __restrict__ WK, const float* __restrict__ bK,
    float* __restrict__ F)
{
    int bx = blockIdx.x;
    int h_i = bx & 7, b = (bx >> 3) & 1, which = bx >> 4;
    int g = h_i >> 1, cc2 = (h_i & 1) * 2;
    int t = threadIdx.x;

    const float* In   = which ? Kin : Qin;
    const float* W    = which ? WK  : WQ;
    const float* bias = which ? bK  : bQ;

    __shared__ float Xl[16][512];
    int sb0 = (h_i & 1) ? 0 : 240;
#pragma unroll
    for (int i = 0; i < 4; ++i) {
        int idx = (i * 512 + t);
        int rl = idx >> 7, m4 = idx & 127;
        int srow = sb0 + (rl >> 3) * 8 + (rl & 7);
        ((float4*)&Xl[rl][0])[m4] =
            ((const float4*)&In[(b * 256 + srow) * 512])[m4];
    }
    __syncthreads();

    int d = t & 63, rr = t >> 6;
    int n = h_i * 64 + d;
    float acc0 = 0.f, acc1 = 0.f;
    const float* wp = W + n;
#pragma unroll 8
    for (int m = 0; m < 512; ++m) {
        float w = wp[m * 512];
        acc0 += Xl[rr][m] * w;
        acc1 += Xl[rr + 8][m] * w;
    }
    float bb = bias[n];
    int base = ((which * 2 + b) * 4 + g) * 4;
    F[(base + cc2)     * 512 + rr * 64 + d] = acc0 + bb;
    F[(base + cc2 + 1) * 512 + rr * 64 + d] = acc1 + bb;
}

// kC: Dt (8-lane dots + shfl) and SFK (pre-scaled x32).  48 blocks x 256 thr.
__global__ void kC_dtab_sfk(const float* __restrict__ F, float* __restrict__ Dt,
                            float* __restrict__ SFK) {
    int slot = blockIdx.x * 256 + threadIdx.x;
    if (slot < 8192) {
        int part = slot & 7, e = slot >> 3;
        int cs = e & 7, cc = (e >> 3) & 3, gk = (e >> 5) & 3,
            gq = (e >> 7) & 3, b = (e >> 9) & 1;
        const float* fq = F + ((b * 4 + gq) * 4 + cc) * 512 + cs * 64 + part * 8;
        const float* fk = F + (((2 + b) * 4 + gk) * 4 + cc) * 512 + cs * 64 + part * 8;
        float a = 0.f;
#pragma unroll
        for (int u = 0; u < 8; ++u) a += fq[u] * fk[u];
        a += __shfl_xor(a, 1);
        a += __shfl_xor(a, 2);
        a += __shfl_xor(a, 4);
        if (part == 0) Dt[e] = a * 0.125f;
    } else {
        int e = slot - 8192;
        int d = e & 63, c = (e >> 6) & 31, b = e >> 11;
        float a = 0.f;
#pragma unroll
        for (int gv = 0; gv < 4; ++gv)
            a += F[(((2 + b) * 4 + gv) * 4 + (c >> 3)) * 512 + (c & 7) * 64 + d];
        SFK[e] = 32.f * a;
    }
}

// kAttn: 1024 blocks x 256 thr.  Wave per (h,q); 2 lanes per k, 16 c each.
__global__ void kAttn(const float* __restrict__ Dt, const void* __restrict__ maskp,
                      const float* __restrict__ SFK, float* __restrict__ ctx,
                      float* __restrict__ attnp, int fill) {
    __shared__ float aws[4][32];
    int vb = blockIdx.x, t = threadIdx.x;
    if (fill) ((float4*)attnp)[vb * 256 + t] = make_float4(1.f, 1.f, 1.f, 1.f);
    int qb = vb & 63, h = (vb >> 6) & 7, b = vb >> 9;
    int wave = t >> 6, l = t & 63;
    int q = qb * 4 + wave;
    int half = l & 1, klo = l >> 1;
    int g_q = q & 3;
    int i_q = h * 32 + (q >> 3);
    bool up_q = (q & 4) == 0;
    int ak = klo & 3;
    bool up_k = (klo & 4) == 0;

    bool mbytes = sniff_mask_bytes((const unsigned int*)maskp);

    float sq[16];
    const float* Db = Dt + ((b * 4 + g_q) * 4 + ak) * 32 + half * 16;
#pragma unroll
    for (int j = 0; j < 16; ++j) {
        int cc = half * 2 + (j >> 3);
        int row = g_q * 64 + 30 + cc;
        bool vq = up_q ? (i_q >= 256 - row) : (i_q <= 255 - row);
        sq[j] = vq ? Db[j] : 0.f;
    }

    float A[16];
#pragma unroll
    for (int j = 0; j < 16; ++j) A[j] = 0.f;

    int qrow = (b * 256 + q) * 256;
    for (int r = 0; r < 8; ++r) {
        int k = r * 32 + klo;
        bool masked = mbytes ? (((const unsigned char*)maskp)[qrow + k] != 0)
                             : (((const int*)maskp)[qrow + k] != 0);
        if (masked) {
#pragma unroll
            for (int j = 0; j < 16; ++j) A[j] += 0.03125f;
            continue;
        }
        int i_k = h * 32 + (k >> 3);
        float s[16];
        float mx = -1e30f;
#pragma unroll
        for (int j = 0; j < 16; ++j) {
            int cc = half * 2 + (j >> 3);
            int row = ak * 64 + 30 + cc;
            bool vk = up_k ? (i_k >= 256 - row) : (i_k <= 255 - row);
            s[j] = vk ? sq[j] : 0.f;
            mx = fmaxf(mx, s[j]);
        }
        mx = fmaxf(mx, __shfl_xor(mx, 1));
        float den = 0.f;
#pragma unroll
        for (int j = 0; j < 16; ++j) { s[j] = __expf(s[j] - mx); den += s[j]; }
        den += __shfl_xor(den, 1);
        float inv = 1.f / den;
#pragma unroll
        for (int j = 0; j < 16; ++j) A[j] += s[j] * inv;
    }

#pragma unroll
    for (int off = 2; off < 64; off <<= 1) {
#pragma unroll
        for (int j = 0; j < 16; ++j) A[j] += __shfl_xor(A[j], off);
    }

    float* aw = aws[wave];
    if (l < 2) {
#pragma unroll
        for (int j = 0; j < 16; ++j) aw[l * 16 + j] = A[j];
    }
    float acc = 0.f;
    const float* S = SFK + b * 2048;
#pragma unroll
    for (int c = 0; c < 32; ++c) acc += aw[c] * S[c * 64 + l];
    ctx[(b * 256 + q) * 512 + h * 64 + l] = acc;
}

// kG4LN: outer-product Wo GEMM + bias + residual + LayerNorm, fused.
// 128 blocks x 512 thr; block = 4 output rows.  Wave w owns m in [w*64,w*64+64):
// loads Wo[m][:] ROW-MAJOR as 2 coalesced float4/lane (independent, streaming,
// register-prefetched), scales by LDS-broadcast ctx[r][m].  Cross-wave reduce
// via LDS (2 passes), then LN in-block.
__global__ __launch_bounds__(512) void kG4LN(
    const float* __restrict__ ctx, const float* __restrict__ Wo,
    const float* __restrict__ bo, const float* __restrict__ Qin,
    const float* __restrict__ gamma, const float* __restrict__ beta,
    float* __restrict__ out)
{
    __shared__ float  Cl[4][512];        // ctx rows, later reused as y-tile
    __shared__ float4 red4[8][4][64];    // 32 KB partial buffer
    __shared__ float  red2[8][2];

    int t = threadIdx.x, r0 = blockIdx.x * 4;
    int w = t >> 6, l = t & 63;

    ((float4*)Cl)[t] = ((const float4*)&ctx[r0 * 512])[t];
    __syncthreads();

    const float4* WoV = (const float4*)Wo;
    const float4* pA = WoV + (size_t)(w * 64) * 128 + l;       // cols l*4..+3
    const float4* pB = pA + 64;                                // cols 256+l*4..+3
    float4 a0A = {0,0,0,0}, a1A = {0,0,0,0}, a2A = {0,0,0,0}, a3A = {0,0,0,0};
    float4 a0B = {0,0,0,0}, a1B = {0,0,0,0}, a2B = {0,0,0,0}, a3B = {0,0,0,0};
    int m0 = w * 64;
    float4 wA = pA[0], wB = pB[0];
#pragma unroll 4
    for (int mm = 0; mm < 63; ++mm) {
        float4 nA = pA[(mm + 1) * 128];
        float4 nB = pB[(mm + 1) * 128];
        float s0 = Cl[0][m0 + mm], s1 = Cl[1][m0 + mm];
        float s2 = Cl[2][m0 + mm], s3 = Cl[3][m0 + mm];
        FMA4(a0A, s0, wA); FMA4(a1A, s1, wA); FMA4(a2A, s2, wA); FMA4(a3A, s3, wA);
        FMA4(a0B, s0, wB); FMA4(a1B, s1, wB); FMA4(a2B, s2, wB); FMA4(a3B, s3, wB);
        wA = nA; wB = nB;
    }
    {
        float s0 = Cl[0][m0 + 63], s1 = Cl[1][m0 + 63];
        float s2 = Cl[2][m0 + 63], s3 = Cl[3][m0 + 63];
        FMA4(a0A, s0, wA); FMA4(a1A, s1, wA); FMA4(a2A, s2, wA); FMA4(a3A, s3, wA);
        FMA4(a0B, s0, wB); FMA4(a1B, s1, wB); FMA4(a2B, s2, wB); FMA4(a3B, s3, wB);
    }

    // pass A: cols [0,256)
    red4[w][0][l] = a0A; red4[w][1][l] = a1A; red4[w][2][l] = a2A; red4[w][3][l] = a3A;
    __syncthreads();
    if (t < 256) {
        int r = t >> 6, c4 = t & 63;
        float4 s = red4[0][r][c4];
#pragma unroll
        for (int w2 = 1; w2 < 8; ++w2) {
            float4 v = red4[w2][r][c4];
            s.x += v.x; s.y += v.y; s.z += v.z; s.w += v.w;
        }
        float4 bb = ((const float4*)bo)[c4];
        float4 qq = ((const float4*)Qin)[(r0 + r) * 128 + c4];
        s.x += bb.x + qq.x; s.y += bb.y + qq.y;
        s.z += bb.z + qq.z; s.w += bb.w + qq.w;
        *(float4*)&Cl[r][c4 * 4] = s;
    }
    __syncthreads();
    // pass B: cols [256,512)
    red4[w][0][l] = a0B; red4[w][1][l] = a1B; red4[w][2][l] = a2B; red4[w][3][l] = a3B;
    __syncthreads();
    if (t < 256) {
        int r = t >> 6, c4 = t & 63;
        float4 s = red4[0][r][c4];
#pragma unroll
        for (int w2 = 1; w2 < 8; ++w2) {
            float4 v = red4[w2][r][c4];
            s.x += v.x; s.y += v.y; s.z += v.z; s.w += v.w;
        }
        float4 bb = ((const float4*)bo)[64 + c4];
        float4 qq = ((const float4*)Qin)[(r0 + r) * 128 + 64 + c4];
        s.x += bb.x + qq.x; s.y += bb.y + qq.y;
        s.z += bb.z + qq.z; s.w += bb.w + qq.w;
        *(float4*)&Cl[r][256 + c4 * 4] = s;
    }
    __syncthreads();

    // LayerNorm: 128 threads per row (2 waves), 4 values each
    int r = t >> 7, c = t & 127;
    float v0 = Cl[r][c], v1 = Cl[r][c + 128], v2 = Cl[r][c + 256], v3 = Cl[r][c + 384];
    float s1 = v0 + v1 + v2 + v3;
    float s2 = v0 * v0 + v1 * v1 + v2 * v2 + v3 * v3;
#pragma unroll
    for (int off = 1; off < 64; off <<= 1) {
        s1 += __shfl_xor(s1, off);
        s2 += __shfl_xor(s2, off);
    }
    if (l == 0) { red2[w][0] = s1; red2[w][1] = s2; }
    __syncthreads();
    float tot1 = red2[2 * r][0] + red2[2 * r + 1][0];
    float tot2 = red2[2 * r][1] + red2[2 * r + 1][1];
    float mu = tot1 * (1.f / 512.f);
    float var = tot2 * (1.f / 512.f) - mu * mu;
    float rs = rsqrtf(var + LN_EPS);
    float* op = out + (r0 + r) * 512;
    op[c]       = (v0 - mu) * rs * gamma[c]       + beta[c];
    op[c + 128] = (v1 - mu) * rs * gamma[c + 128] + beta[c + 128];
    op[c + 256] = (v2 - mu) * rs * gamma[c + 256] + beta[c + 256];
    op[c + 384] = (v3 - mu) * rs * gamma[c + 384] + beta[c + 384];
}

// plan-B only: restore attn_out region (which hosted scratch) to 1.0
__global__ void k5_fill(float* __restrict__ p, int n) {
    int i = (blockIdx.x * 256 + threadIdx.x) * 4;
    float4 one = make_float4(1.f, 1.f, 1.f, 1.f);
    for (; i < n; i += gridDim.x * 256 * 4) *(float4*)(p + i) = one;
}

extern "C" void kernel_launch(void* const* d_in, const int* in_sizes, int n_in,
                              void* d_out, int out_size, void* d_ws, size_t ws_size,
                              hipStream_t stream) {
    (void)in_sizes; (void)n_in; (void)out_size;
    const float* Qin  = (const float*)d_in[0];
    const float* Kin  = (const float*)d_in[1];
    const void*  mask = d_in[3];
    const float* WQ   = (const float*)d_in[4];
    const float* bQ   = (const float*)d_in[5];
    const float* WK   = (const float*)d_in[6];
    const float* bK   = (const float*)d_in[7];
    const float* Wo   = (const float*)d_in[10];
    const float* bo   = (const float*)d_in[11];
    const float* gamma= (const float*)d_in[12];
    const float* beta = (const float*)d_in[13];

    float* out   = (float*)d_out;
    float* attnp = out + 262144;                  // 1,048,576 floats (output 1)

    const size_t NEED = 300032ull * sizeof(float);
    int fill;
    float* scr;
    if (ws_size >= NEED) { scr = (float*)d_ws; fill = 1; }   // plan A
    else                 { scr = attnp;        fill = 0; }   // plan B

    float* F   = scr;                             // 32768
    float* Dt  = scr + 32768;                     // 1024
    float* SFK = scr + 33792;                     // 4096 (pre-scaled x32)
    float* ctx = scr + 37888;                     // 262144

    kP_proj    <<<dim3(64),   dim3(512), 0, stream>>>(Qin, Kin, WQ, bQ, WK, bK, F);
    kC_dtab_sfk<<<dim3(48),   dim3(256), 0, stream>>>(F, Dt, SFK);
    kAttn      <<<dim3(1024), dim3(256), 0, stream>>>(Dt, mask, SFK, ctx, attnp, fill);
    kG4LN      <<<dim3(128),  dim3(512), 0, stream>>>(ctx, Wo, bo, Qin, gamma, beta, out);
    if (!fill) k5_fill<<<dim3(256), dim3(256), 0, stream>>>(attnp, 1048576);
}